// Round 9
// baseline (4270.876 us; speedup 1.0000x reference)
//
#include <hip/hip_runtime.h>
#include <hip/hip_fp16.h>

// IGIRNN persistent-scan kernel, round 9.
// Round-8 analysis: step = 7.2K cyc vs ~2.7K hop-model -> hidden costs are
// gather fabric burst (8MB/step through LLC) + per-step straggler max over
// 32 publisher WGs. Round 9 keeps the PROVEN round-8 protocol (sc0 sc1
// atomics, monolithic asm gather w/ internal vmcnt(0), one barrier/step,
// flag-stamp induction, poll-ALL-flags safety proof) and reshapes:
//  - 16 WGs/group x 64 j-cols (grid 128): gather volume 8->4 MB/step,
//    straggler set 32->16, poll noise halved.
//  - Symmetric waves: each wave gathers 4 writers (8x16B, same asm),
//    computes 4 j-tile partials (32 MFMA, 4 indep acc chains), finalizes
//    tile w (3-partial LDS reduce), publishes 512B + per-wave flag
//    (64 flags/group = 1/lane to poll).
//  - gate_x in REGISTERS: wave's gx tile == its own j-tile; MFMA C-layout
//    matches pointwise ownership exactly -> gxch LDS deleted.
// Chunk = 2KB [m-half][batch*64 + quad*16] fragment order; writer wave w
// lane (col,quad) stores 8B at m=(w>>1), k'=(w&1)*16+row4 (desk-checked
// against consumer frag (m,quad,col) mapping).

#define BB 128
#define TT 1024
#define ID 256
#define HH 1024

using f16   = _Float16;
using f16x8 = __attribute__((ext_vector_type(8))) _Float16;
using f32x4 = __attribute__((ext_vector_type(4))) float;
typedef unsigned long long u64;

// LDS (bytes)
#define OFF_X    0        // x   [2][16][512B] f16, SWZ  = 16384
#define OFF_GH   16384    // ghT [2][4 src][4 nt][272] f32 = 34816
#define LDS_SIZE 51200

#define SWZ(row, kbyte) ((kbyte) ^ (((row) & 3) << 4))
#define MFMA16(a, b, c) __builtin_amdgcn_mfma_f32_16x16x32_f16(a, b, c, 0, 0, 0)

static __device__ __forceinline__ void store4h(f16* dst, float a, float b, float c, float d) {
  union { f16 h[4]; u64 u; } p;
  p.h[0] = (f16)a; p.h[1] = (f16)b; p.h[2] = (f16)c; p.h[3] = (f16)d;
  *reinterpret_cast<u64*>(dst) = p.u;
}

static __device__ __forceinline__ f16x8 cvt8(float4 a, float4 b) {
  f16x8 r;
  r[0] = (f16)a.x; r[1] = (f16)a.y; r[2] = (f16)a.z; r[3] = (f16)a.w;
  r[4] = (f16)b.x; r[5] = (f16)b.y; r[6] = (f16)b.z; r[7] = (f16)b.w;
  return r;
}

static __device__ __forceinline__ void put_tile(float* dst, f32x4 v, int lane) {
  const int c = lane & 15, r4 = (lane >> 4) * 4;
  #pragma unroll
  for (int r = 0; r < 4; ++r) dst[(r4 + r) * 17 + c] = v[r];
}

__global__ __launch_bounds__(256, 1) void rnn_core(
    const float* __restrict__ x, const float* __restrict__ Wx, const float* __restrict__ bx,
    const float* __restrict__ Wh, const float* __restrict__ bh,
    f16* __restrict__ hbuf,      // [2 parity][8 grp][16 wg][2KB chunk] = 512KB
    float* __restrict__ hfin,    // [128][1024] f32
    int* __restrict__ flags)     // [8][16 wg][4 wave] stamps, 64B-strided
{
  extern __shared__ char lds[];
  char*  xbuf = lds + OFF_X;              // [2][16][512B], SWZ
  float* ghT  = (float*)(lds + OFF_GH);   // [2][4 src][4 nt][272]

  const int tid  = threadIdx.x;
  const int lane = tid & 63;
  const int w    = tid >> 6;
  const int g    = blockIdx.x & 7;
  const int cw   = blockIdx.x >> 3;       // 0..15
  const int b0   = g * 16;
  const int j0   = cw * 64;
  const int col  = lane & 15;
  const int quad = lane >> 4;
  const int row4 = quad * 4;

  // ---- Wh A-fragments -> registers: whf[nt*8+i] covers k-chunk w*8+i ----
  f16x8 whf[32];
  #pragma unroll
  for (int nt = 0; nt < 4; ++nt)
    #pragma unroll
    for (int i = 0; i < 8; ++i) {
      const float* p = Wh + (size_t)(j0 + nt * 16 + col) * HH + ((w << 3) + i) * 32 + quad * 8;
      whf[nt * 8 + i] = cvt8(*reinterpret_cast<const float4*>(p),
                             *reinterpret_cast<const float4*>(p + 4));
    }
  // ---- Wx A-fragments: wave's own j-tile w, both gates ----
  f16x8 wxf[16];
  #pragma unroll
  for (int gt = 0; gt < 2; ++gt)
    #pragma unroll
    for (int ks = 0; ks < 8; ++ks) {
      const float* p = Wx + (size_t)(gt * HH + j0 + w * 16 + col) * ID + ks * 32 + quad * 8;
      wxf[gt * 8 + ks] = cvt8(*reinterpret_cast<const float4*>(p),
                              *reinterpret_cast<const float4*>(p + 4));
    }

  // biases at j = j0 + w*16 + row4 (+r)
  const float4 bh4  = *reinterpret_cast<const float4*>(bh + j0 + w * 16 + row4);
  const float4 bxr4 = *reinterpret_cast<const float4*>(bx + j0 + w * 16 + row4);
  const float4 bxi4 = *reinterpret_cast<const float4*>(bx + HH + j0 + w * 16 + row4);

  // ---- prologue: stage x(0)->slot0, x(1)->slot1 ----
  for (int s = 0; s < 2; ++s)
    for (int c = tid; c < 1024; c += 256) {
      int row = c >> 6, k4 = c & 63;
      float4 v = *reinterpret_cast<const float4*>(
          x + ((size_t)(b0 + row) * TT + s) * ID + k4 * 4);
      store4h((f16*)(xbuf + s * 8192 + row * 512 + SWZ(row, k4 * 8)), v.x, v.y, v.z, v.w);
    }
  __syncthreads();

  // ---- gx(0) -> parity-0 registers (own j-tile: C-layout == ownership) ----
  f32x4 gxr0 = {0,0,0,0}, gxi0 = {0,0,0,0}, gxr1 = {0,0,0,0}, gxi1 = {0,0,0,0};
  {
    const char* pxb = xbuf + col * 512 + ((quad * 16) ^ ((col & 3) << 4));
    #pragma unroll
    for (int ks = 0; ks < 8; ++ks) {
      f16x8 bfr = *reinterpret_cast<const f16x8*>(pxb + ks * 64);
      gxr0 = MFMA16(wxf[ks], bfr, gxr0);
      gxi0 = MFMA16(wxf[8 + ks], bfr, gxi0);
    }
  }

  float hm[4] = {0.f, 0.f, 0.f, 0.f};     // h[b0+col][j0+w*16+row4+r]

  // invariant addresses
  const unsigned gvo = (unsigned)(col * 64 + quad * 16);
  const u64 hb0 = (u64)((const char*)hbuf + (size_t)g * 32768 + (size_t)w * 8192) + gvo;
  const u64 hb1 = hb0 + 262144;
  const int kp  = ((w & 1) << 4) + row4;
  const u64 pb0 = (u64)((char*)hbuf + (size_t)g * 32768 + (size_t)cw * 2048
                        + (w >> 1) * 1024 + col * 64 + (kp >> 3) * 16 + (kp & 7) * 2);
  const u64 pb1 = pb0 + 262144;
  int* myflag = flags + ((g * 64) + cw * 4 + w) * 16;
  const int* pollp = flags + ((g * 64) + lane) * 16;

  for (int t = 0; t < TT; ++t) {
    const int p = t & 1;
    // ======== region A: poll(64) -> gather 8x16B -> 32 MFMA (4 accs) ========
    f32x4 a0 = {0,0,0,0}, a1 = {0,0,0,0}, a2 = {0,0,0,0}, a3 = {0,0,0,0};
    if (t > 0) {
      int v;
      do { v = __hip_atomic_load(pollp, __ATOMIC_RELAXED, __HIP_MEMORY_SCOPE_SYSTEM);
      } while (!__all(v >= t));

      u64 ad0 = p ? hb1 : hb0;
      u64 ad1 = ad0 + 4096;
      f32x4 f0, f1, f2, f3, f4, f5, f6, f7;
      asm volatile(
        "global_load_dwordx4 %0, %8, off sc0 sc1\n\t"
        "global_load_dwordx4 %1, %8, off offset:1024 sc0 sc1\n\t"
        "global_load_dwordx4 %2, %8, off offset:2048 sc0 sc1\n\t"
        "global_load_dwordx4 %3, %8, off offset:3072 sc0 sc1\n\t"
        "global_load_dwordx4 %4, %9, off sc0 sc1\n\t"
        "global_load_dwordx4 %5, %9, off offset:1024 sc0 sc1\n\t"
        "global_load_dwordx4 %6, %9, off offset:2048 sc0 sc1\n\t"
        "global_load_dwordx4 %7, %9, off offset:3072 sc0 sc1\n\t"
        "s_waitcnt vmcnt(0)"
        : "=&v"(f0), "=&v"(f1), "=&v"(f2), "=&v"(f3),
          "=&v"(f4), "=&v"(f5), "=&v"(f6), "=&v"(f7)
        : "v"(ad0), "v"(ad1) : "memory");

      #define STEPM(i, F) { f16x8 bf_ = *reinterpret_cast<f16x8*>(&F); \
        a0 = MFMA16(whf[i], bf_, a0);      a1 = MFMA16(whf[8 + (i)], bf_, a1); \
        a2 = MFMA16(whf[16 + (i)], bf_, a2); a3 = MFMA16(whf[24 + (i)], bf_, a3); }
      STEPM(0, f0) STEPM(1, f1) STEPM(2, f2) STEPM(3, f3)
      STEPM(4, f4) STEPM(5, f5) STEPM(6, f6) STEPM(7, f7)
      #undef STEPM
    }
    // export partials for tiles != own (slot = src*4 + nt)
    float* ghp = ghT + p * 4352;
    if (w != 0) put_tile(ghp + (w * 4 + 0) * 272, a0, lane);
    if (w != 1) put_tile(ghp + (w * 4 + 1) * 272, a1, lane);
    if (w != 2) put_tile(ghp + (w * 4 + 2) * 272, a2, lane);
    if (w != 3) put_tile(ghp + (w * 4 + 3) * 272, a3, lane);

    __syncthreads();                                  // the ONE barrier/step

    // ======== region B: reduce + pointwise + publish + flag, then gx/prefetch
    {
      f32x4 own = (w == 0) ? a0 : ((w == 1) ? a1 : ((w == 2) ? a2 : a3));
      f32x4 cgr = p ? gxr1 : gxr0;
      f32x4 cgi = p ? gxi1 : gxi0;
      float hn[4];
      #pragma unroll
      for (int r = 0; r < 4; ++r) {
        int idx = (row4 + r) * 17 + col;
        float s = own[r] + ((const float*)&bh4)[r];
        if (w != 0) s += ghp[(0 * 4 + w) * 272 + idx];
        if (w != 1) s += ghp[(1 * 4 + w) * 272 + idx];
        if (w != 2) s += ghp[(2 * 4 + w) * 272 + idx];
        if (w != 3) s += ghp[(3 * 4 + w) * 272 + idx];
        float ir  = cgr[r] + ((const float*)&bxr4)[r];
        float ii  = cgi[r] + ((const float*)&bxi4)[r];
        float rg  = 1.f / (1.f + __expf(-ir));
        float ig  = 1.f / (1.f + __expf(-ii));
        float z   = rg * s;
        z = fminf(fmaxf(z, -15.f), 15.f);
        float e   = __expf(-2.f * z);
        float ng  = (1.f - e) / (1.f + e);
        float h_  = ng + ig * (hm[r] - ng);
        hm[r] = h_; hn[r] = h_;
      }
      union { f16 h[4]; u64 uu; } pk;
      pk.h[0] = (f16)hn[0]; pk.h[1] = (f16)hn[1]; pk.h[2] = (f16)hn[2]; pk.h[3] = (f16)hn[3];
      u64* adp = (u64*)(p ? pb0 : pb1);               // h(t+1) -> parity (t+1)&1
      __hip_atomic_store(adp, pk.uu, __ATOMIC_RELAXED, __HIP_MEMORY_SCOPE_SYSTEM);
      asm volatile("s_waitcnt vmcnt(0)" ::: "memory"); // data before flag
      if (lane == 0)
        __hip_atomic_store(myflag, t + 1, __ATOMIC_RELAXED, __HIP_MEMORY_SCOPE_SYSTEM);
    }
    // gx(t+1) -> parity (p^1) registers (reads x slot (t+1)&1 = p^1)
    if (t + 1 < TT) {
      f32x4 tr = {0,0,0,0}, ti = {0,0,0,0};
      const char* pxb = xbuf + (p ^ 1) * 8192 + col * 512 + ((quad * 16) ^ ((col & 3) << 4));
      #pragma unroll
      for (int ks = 0; ks < 8; ++ks) {
        f16x8 bfr = *reinterpret_cast<const f16x8*>(pxb + ks * 64);
        tr = MFMA16(wxf[ks], bfr, tr);
        ti = MFMA16(wxf[8 + ks], bfr, ti);
      }
      if (p) { gxr0 = tr; gxi0 = ti; } else { gxr1 = tr; gxi1 = ti; }
    }
    // x(t+2) prefetch -> slot t&1 (read by gx(t+2) at step t+1, after barrier)
    if (t + 2 < TT) {
      char* xd = xbuf + p * 8192;
      #pragma unroll
      for (int it = 0; it < 4; ++it) {
        int c = tid + it * 256;
        int row = c >> 6, k4 = c & 63;
        float4 v = *reinterpret_cast<const float4*>(
            x + ((size_t)(b0 + row) * TT + (t + 2)) * ID + k4 * 4);
        store4h((f16*)(xd + row * 512 + SWZ(row, k4 * 8)), v.x, v.y, v.z, v.w);
      }
    }
  }

  // ---- final h export ----
  {
    float4 o; o.x = hm[0]; o.y = hm[1]; o.z = hm[2]; o.w = hm[3];
    *reinterpret_cast<float4*>(hfin + (size_t)(b0 + col) * HH + j0 + w * 16 + row4) = o;
  }
}

// out[b][o] = hfin[b][:] . Wfc[o][:] + bfc[o];  128x256, K=1024.
__global__ __launch_bounds__(64) void fc_kernel(
    const float* __restrict__ hfin, const float* __restrict__ Wfc,
    const float* __restrict__ bfc, float* __restrict__ out)
{
  const int lane = threadIdx.x;
  const int mb = blockIdx.x >> 4, nb = blockIdx.x & 15;
  const int col = lane & 15, row4 = (lane >> 4) * 4;
  const float* pa = hfin + (size_t)(mb * 16 + (lane & 15)) * HH + (lane >> 4) * 8;
  const float* pb = Wfc  + (size_t)(nb * 16 + (lane & 15)) * HH + (lane >> 4) * 8;
  f32x4 acc = {0.f, 0.f, 0.f, 0.f};
  for (int kc = 0; kc < 32; ++kc) {
    f16x8 a, b;
    #pragma unroll
    for (int e = 0; e < 8; ++e) {
      a[e] = (f16)pa[kc * 32 + e];
      b[e] = (f16)pb[kc * 32 + e];
    }
    acc = __builtin_amdgcn_mfma_f32_16x16x32_f16(a, b, acc, 0, 0, 0);
  }
  float bias = bfc[nb * 16 + col];
  #pragma unroll
  for (int r = 0; r < 4; ++r)
    out[(size_t)(mb * 16 + row4 + r) * 256 + nb * 16 + col] = acc[r] + bias;
}

extern "C" void kernel_launch(void* const* d_in, const int* in_sizes, int n_in,
                              void* d_out, int out_size, void* d_ws, size_t ws_size,
                              hipStream_t stream) {
  const float* x   = (const float*)d_in[0];
  const float* Wx  = (const float*)d_in[1];
  const float* bx  = (const float*)d_in[2];
  const float* Wh  = (const float*)d_in[3];
  const float* bh  = (const float*)d_in[4];
  const float* Wfc = (const float*)d_in[5];
  const float* bfc = (const float*)d_in[6];
  float* out = (float*)d_out;

  char* ws = (char*)d_ws;
  f16*   hbuf  = (f16*)ws;                 // 512KB chunk exchange
  float* hfin  = (float*)(ws + 524288);    // 512KB
  int*   flags = (int*)(ws + 1048576);     // 32KB ([8][16][4] x 64B)

  hipMemsetAsync(flags, 0, 32768, stream); // stamps monotone within one run

  (void)hipFuncSetAttribute((const void*)rnn_core,
                            hipFuncAttributeMaxDynamicSharedMemorySize, LDS_SIZE);

  void* args[8];
  args[0] = (void*)&x;    args[1] = (void*)&Wx;   args[2] = (void*)&bx;
  args[3] = (void*)&Wh;   args[4] = (void*)&bh;   args[5] = (void*)&hbuf;
  args[6] = (void*)&hfin; args[7] = (void*)&flags;
  hipError_t err = hipLaunchCooperativeKernel((void*)rnn_core, dim3(128), dim3(256),
                                              args, LDS_SIZE, stream);
  if (err != hipSuccess) {
    rnn_core<<<dim3(128), dim3(256), LDS_SIZE, stream>>>(x, Wx, bx, Wh, bh, hbuf, hfin, flags);
  }

  fc_kernel<<<dim3(128), dim3(64), 0, stream>>>(hfin, Wfc, bfc, out);
}